// Round 13
// baseline (1469.372 us; speedup 1.0000x reference)
//
#include <hip/hip_runtime.h>
#include <math.h>

#define N_NODES 100000
#define N_EDGES 1600000
#define N_GRAPHS 256
#define BN_EPS 1e-5f

// ---------------- CSR build ----------------
__global__ void hist_kernel(const int* __restrict__ ei, int* __restrict__ deg) {
    int e = blockIdx.x * blockDim.x + threadIdx.x;
    if (e < N_EDGES) atomicAdd(&deg[ei[N_EDGES + e]], 1);
}

__global__ void scan1_kernel(const int* __restrict__ deg, int* __restrict__ rowptr,
                             int* __restrict__ bsum) {
    __shared__ int s[256];
    int tid = threadIdx.x;
    int i = blockIdx.x * 256 + tid;
    int v = (i < N_NODES) ? deg[i] : 0;
    s[tid] = v; __syncthreads();
    for (int off = 1; off < 256; off <<= 1) {
        int t = (tid >= off) ? s[tid - off] : 0; __syncthreads();
        s[tid] += t; __syncthreads();
    }
    if (i < N_NODES) rowptr[i] = s[tid] - v;   // exclusive
    if (tid == 255) bsum[blockIdx.x] = s[255];
}

__global__ void scan2_kernel(int* bsum, int nb) {
    __shared__ int s[512];
    int tid = threadIdx.x;
    int v = (tid < nb) ? bsum[tid] : 0;
    s[tid] = v; __syncthreads();
    for (int off = 1; off < 512; off <<= 1) {
        int t = (tid >= off) ? s[tid - off] : 0; __syncthreads();
        s[tid] += t; __syncthreads();
    }
    if (tid < nb) bsum[tid] = s[tid] - v;      // exclusive
}

__global__ void scan3_kernel(int* __restrict__ rowptr, const int* __restrict__ bsum) {
    int i = blockIdx.x * 256 + threadIdx.x;
    if (i < N_NODES) rowptr[i] += bsum[blockIdx.x];
    if (i == 0) rowptr[N_NODES] = N_EDGES;
}

__global__ void scatter_kernel(const int* __restrict__ ei, const float* __restrict__ ew,
                               const int* __restrict__ rowptr, int* __restrict__ cnt,
                               int* __restrict__ ssrc, float* __restrict__ swt) {
    int e = blockIdx.x * blockDim.x + threadIdx.x;
    if (e >= N_EDGES) return;
    int dst = ei[N_EDGES + e];
    int pos = rowptr[dst] + atomicAdd(&cnt[dst], 1);
    ssrc[pos] = ei[e];
    swt[pos] = ew[e];
}

// ---------------- fused prep: pad_x + starts + bnprep (one launch) ----------------
__global__ __launch_bounds__(256) void prep_kernel(const float* __restrict__ x,
        float* __restrict__ xp, const int* __restrict__ batch,
        int* __restrict__ starts, const float* __restrict__ v1,
        const float* __restrict__ v2, const float* __restrict__ v3,
        float* __restrict__ rs) {
    int i = blockIdx.x * 256 + threadIdx.x;
    if (i < N_NODES * 32) {
        int n = i >> 5, c = i & 31;
        xp[i] = (c < 29) ? x[n * 29 + c] : 0.f;
    }
    if (i < N_NODES) {
        int b = batch[i];
        int bp = (i == 0) ? -1 : batch[i - 1];
        for (int g = bp + 1; g <= b; ++g) starts[g] = i;
        if (i == N_NODES - 1)
            for (int g = b + 1; g <= N_GRAPHS; ++g) starts[g] = N_NODES;
    }
    if (blockIdx.x == 12499) {
        int t = threadIdx.x;
        if (t < 128) rs[t] = 1.0f / sqrtf(v1[t] + BN_EPS);
        if (t < 64)  rs[128 + t] = 1.0f / sqrtf(v2[t] + BN_EPS);
        if (t < 32)  rs[192 + t] = 1.0f / sqrtf(v3[t] + BN_EPS);
    }
}

// ---------------- layer-1 gather on padded x: agg[N,32] ----------------
__global__ __launch_bounds__(256) void agg_x_kernel(const float* __restrict__ xp,
        const int* __restrict__ rowptr, const int* __restrict__ ssrc,
        const float* __restrict__ swt, float* __restrict__ agg) {
    int tid = threadIdx.x;
    int node = blockIdx.x * 32 + (tid >> 3);
    int c = (tid & 7) * 4;
    int e0 = rowptr[node], e1 = rowptr[node + 1];
    float4 acc = {0.f, 0.f, 0.f, 0.f};
    int e = e0;
    // align e to 4 (order-preserving)
    for (; e < e1 && (e & 3); ++e) {
        int s0 = ssrc[e]; float w0 = swt[e];
        float4 y0 = *(const float4*)&xp[(size_t)s0 * 32 + c];
        acc.x = fmaf(w0, y0.x, acc.x); acc.y = fmaf(w0, y0.y, acc.y);
        acc.z = fmaf(w0, y0.z, acc.z); acc.w = fmaf(w0, y0.w, acc.w);
    }
    for (; e + 8 <= e1; e += 8) {
        int4   sa = *(const int4*)&ssrc[e];
        int4   sb = *(const int4*)&ssrc[e + 4];
        float4 wa = *(const float4*)&swt[e];
        float4 wb = *(const float4*)&swt[e + 4];
        float4 y0 = *(const float4*)&xp[(size_t)sa.x * 32 + c];
        float4 y1 = *(const float4*)&xp[(size_t)sa.y * 32 + c];
        float4 y2 = *(const float4*)&xp[(size_t)sa.z * 32 + c];
        float4 y3 = *(const float4*)&xp[(size_t)sa.w * 32 + c];
        float4 y4 = *(const float4*)&xp[(size_t)sb.x * 32 + c];
        float4 y5 = *(const float4*)&xp[(size_t)sb.y * 32 + c];
        float4 y6 = *(const float4*)&xp[(size_t)sb.z * 32 + c];
        float4 y7 = *(const float4*)&xp[(size_t)sb.w * 32 + c];
        acc.x = fmaf(wa.x, y0.x, acc.x); acc.y = fmaf(wa.x, y0.y, acc.y);
        acc.z = fmaf(wa.x, y0.z, acc.z); acc.w = fmaf(wa.x, y0.w, acc.w);
        acc.x = fmaf(wa.y, y1.x, acc.x); acc.y = fmaf(wa.y, y1.y, acc.y);
        acc.z = fmaf(wa.y, y1.z, acc.z); acc.w = fmaf(wa.y, y1.w, acc.w);
        acc.x = fmaf(wa.z, y2.x, acc.x); acc.y = fmaf(wa.z, y2.y, acc.y);
        acc.z = fmaf(wa.z, y2.z, acc.z); acc.w = fmaf(wa.z, y2.w, acc.w);
        acc.x = fmaf(wa.w, y3.x, acc.x); acc.y = fmaf(wa.w, y3.y, acc.y);
        acc.z = fmaf(wa.w, y3.z, acc.z); acc.w = fmaf(wa.w, y3.w, acc.w);
        acc.x = fmaf(wb.x, y4.x, acc.x); acc.y = fmaf(wb.x, y4.y, acc.y);
        acc.z = fmaf(wb.x, y4.z, acc.z); acc.w = fmaf(wb.x, y4.w, acc.w);
        acc.x = fmaf(wb.y, y5.x, acc.x); acc.y = fmaf(wb.y, y5.y, acc.y);
        acc.z = fmaf(wb.y, y5.z, acc.z); acc.w = fmaf(wb.y, y5.w, acc.w);
        acc.x = fmaf(wb.z, y6.x, acc.x); acc.y = fmaf(wb.z, y6.y, acc.y);
        acc.z = fmaf(wb.z, y6.z, acc.z); acc.w = fmaf(wb.z, y6.w, acc.w);
        acc.x = fmaf(wb.w, y7.x, acc.x); acc.y = fmaf(wb.w, y7.y, acc.y);
        acc.z = fmaf(wb.w, y7.z, acc.z); acc.w = fmaf(wb.w, y7.w, acc.w);
    }
    for (; e + 4 <= e1; e += 4) {
        int4   s4 = *(const int4*)&ssrc[e];
        float4 w4 = *(const float4*)&swt[e];
        float4 y0 = *(const float4*)&xp[(size_t)s4.x * 32 + c];
        float4 y1 = *(const float4*)&xp[(size_t)s4.y * 32 + c];
        float4 y2 = *(const float4*)&xp[(size_t)s4.z * 32 + c];
        float4 y3 = *(const float4*)&xp[(size_t)s4.w * 32 + c];
        acc.x = fmaf(w4.x, y0.x, acc.x); acc.y = fmaf(w4.x, y0.y, acc.y);
        acc.z = fmaf(w4.x, y0.z, acc.z); acc.w = fmaf(w4.x, y0.w, acc.w);
        acc.x = fmaf(w4.y, y1.x, acc.x); acc.y = fmaf(w4.y, y1.y, acc.y);
        acc.z = fmaf(w4.y, y1.z, acc.z); acc.w = fmaf(w4.y, y1.w, acc.w);
        acc.x = fmaf(w4.z, y2.x, acc.x); acc.y = fmaf(w4.z, y2.y, acc.y);
        acc.z = fmaf(w4.z, y2.z, acc.z); acc.w = fmaf(w4.z, y2.w, acc.w);
        acc.x = fmaf(w4.w, y3.x, acc.x); acc.y = fmaf(w4.w, y3.y, acc.y);
        acc.z = fmaf(w4.w, y3.z, acc.z); acc.w = fmaf(w4.w, y3.w, acc.w);
    }
    for (; e < e1; ++e) {
        int s0 = ssrc[e]; float w0 = swt[e];
        float4 y0 = *(const float4*)&xp[(size_t)s0 * 32 + c];
        acc.x = fmaf(w0, y0.x, acc.x); acc.y = fmaf(w0, y0.y, acc.y);
        acc.z = fmaf(w0, y0.z, acc.z); acc.w = fmaf(w0, y0.w, acc.w);
    }
    *(float4*)&agg[(size_t)node * 32 + c] = acc;
}

// h1 = relu(agg @ w1_rel + b1 + x @ w1_root), [N,256]; agg/xp padded stride 32.
// 64 rows/block; LDS reads wave-uniform broadcasts; fmaf chain bit-exact.
__global__ __launch_bounds__(256) void dense1_kernel(const float* __restrict__ agg,
        const float* __restrict__ xp, const float* __restrict__ wrel,
        const float* __restrict__ wroot, const float* __restrict__ bias,
        float* __restrict__ out) {
    __shared__ float sA[64 * 32];
    __shared__ float sX[64 * 32];
    int tid = threadIdx.x;
    size_t node0 = (size_t)blockIdx.x * 64;
    for (int idx = tid; idx < 512; idx += 256) {
        ((float4*)sA)[idx] = ((const float4*)(agg + node0 * 32))[idx];
        ((float4*)sX)[idx] = ((const float4*)(xp + node0 * 32))[idx];
    }
    __syncthreads();
    int ct = tid & 63;      // 64 col-tiles of 4
    int mg = tid >> 6;      // 4 m-groups of 16 rows
    int c0 = ct * 4;
    float acc[16][4];
#pragma unroll
    for (int m = 0; m < 16; m++)
#pragma unroll
        for (int j = 0; j < 4; j++) acc[m][j] = 0.f;
    for (int k0 = 0; k0 < 28; k0 += 4) {
        float4 wr[4], wo[4];
#pragma unroll
        for (int j = 0; j < 4; j++) {
            wr[j] = *(const float4*)&wrel[(k0 + j) * 256 + c0];
            wo[j] = *(const float4*)&wroot[(k0 + j) * 256 + c0];
        }
#pragma unroll
        for (int m = 0; m < 16; m++) {
            float4 av = *(const float4*)&sA[(mg * 16 + m) * 32 + k0];
            float4 xv = *(const float4*)&sX[(mg * 16 + m) * 32 + k0];
            float as[4] = {av.x, av.y, av.z, av.w};
            float xs[4] = {xv.x, xv.y, xv.z, xv.w};
#pragma unroll
            for (int j = 0; j < 4; j++) {
                acc[m][0] = fmaf(as[j], wr[j].x, fmaf(xs[j], wo[j].x, acc[m][0]));
                acc[m][1] = fmaf(as[j], wr[j].y, fmaf(xs[j], wo[j].y, acc[m][1]));
                acc[m][2] = fmaf(as[j], wr[j].z, fmaf(xs[j], wo[j].z, acc[m][2]));
                acc[m][3] = fmaf(as[j], wr[j].w, fmaf(xs[j], wo[j].w, acc[m][3]));
            }
        }
    }
    {   // tail k = 28
        float4 wr = *(const float4*)&wrel[28 * 256 + c0];
        float4 wo = *(const float4*)&wroot[28 * 256 + c0];
#pragma unroll
        for (int m = 0; m < 16; m++) {
            float sa = sA[(mg * 16 + m) * 32 + 28];
            float sx = sX[(mg * 16 + m) * 32 + 28];
            acc[m][0] = fmaf(sa, wr.x, fmaf(sx, wo.x, acc[m][0]));
            acc[m][1] = fmaf(sa, wr.y, fmaf(sx, wo.y, acc[m][1]));
            acc[m][2] = fmaf(sa, wr.z, fmaf(sx, wo.z, acc[m][2]));
            acc[m][3] = fmaf(sa, wr.w, fmaf(sx, wo.w, acc[m][3]));
        }
    }
    float4 b4 = *(const float4*)&bias[c0];
#pragma unroll
    for (int m = 0; m < 16; m++) {
        size_t row = node0 + mg * 16 + m;
        float4 o;
        o.x = fmaxf(acc[m][0] + b4.x, 0.f);
        o.y = fmaxf(acc[m][1] + b4.y, 0.f);
        o.z = fmaxf(acc[m][2] + b4.z, 0.f);
        o.w = fmaxf(acc[m][3] + b4.w, 0.f);
        *(float4*)&out[row * 256 + c0] = o;
    }
}

// ---------------- dual GEMM: y = in@wA, r = in@wB  ([N,K] @ [K,F]) ----------------
// R4 structure, converged (8 schedule variants null/worse). 52 VGPR fits 8
// waves/EU -> (256,8) hint targets the anomalous 33% OccupancyPercent (2.6
// blocks/CU resident vs 8 allowed by resources). Zero spill risk.
template <int K, int F, int RPM, int KC>
__global__ __launch_bounds__(256, 8) void gemm_dual_kernel(const float* __restrict__ in,
        const float* __restrict__ wA, const float* __restrict__ wB,
        float* __restrict__ outA, float* __restrict__ outB) {
    constexpr int NT = 256;
    constexpr int NCT = F / 2;        // col-groups of 4 over 2F output cols
    constexpr int MG = NT / NCT;
    constexpr int ROWS = MG * RPM;
    constexpr int KC4 = KC / 4;
    __shared__ float s[ROWS * KC];
    int tid = threadIdx.x;
    size_t node0 = (size_t)blockIdx.x * ROWS;
    int ct = tid % NCT;
    int mg = tid / NCT;
    int c0 = ct * 4;
    const float* W;
    float* OUT;
    int cc;
    if (c0 < F) { W = wA; OUT = outA; cc = c0; }
    else        { W = wB; OUT = outB; cc = c0 - F; }
    float acc[RPM][4];
#pragma unroll
    for (int m = 0; m < RPM; m++)
#pragma unroll
        for (int j = 0; j < 4; j++) acc[m][j] = 0.f;
    const float* srow = s + (size_t)(mg * RPM) * KC;
    for (int kb = 0; kb < K; kb += KC) {
        __syncthreads();
        for (int idx = tid; idx < ROWS * KC4; idx += NT) {
            int rr = idx / KC4;
            int c4 = idx % KC4;
            *(float4*)&s[rr * KC + c4 * 4] =
                *(const float4*)&in[(node0 + rr) * K + kb + c4 * 4];
        }
        __syncthreads();
        for (int k0 = 0; k0 < KC; k0 += 4) {
            float4 w0 = *(const float4*)&W[(kb + k0 + 0) * F + cc];
            float4 w1 = *(const float4*)&W[(kb + k0 + 1) * F + cc];
            float4 w2 = *(const float4*)&W[(kb + k0 + 2) * F + cc];
            float4 w3 = *(const float4*)&W[(kb + k0 + 3) * F + cc];
#pragma unroll
            for (int m = 0; m < RPM; m++) {
                float4 sm = *(const float4*)&srow[m * KC + k0];
                acc[m][0] = fmaf(sm.x, w0.x, acc[m][0]);
                acc[m][1] = fmaf(sm.x, w0.y, acc[m][1]);
                acc[m][2] = fmaf(sm.x, w0.z, acc[m][2]);
                acc[m][3] = fmaf(sm.x, w0.w, acc[m][3]);
                acc[m][0] = fmaf(sm.y, w1.x, acc[m][0]);
                acc[m][1] = fmaf(sm.y, w1.y, acc[m][1]);
                acc[m][2] = fmaf(sm.y, w1.z, acc[m][2]);
                acc[m][3] = fmaf(sm.y, w1.w, acc[m][3]);
                acc[m][0] = fmaf(sm.z, w2.x, acc[m][0]);
                acc[m][1] = fmaf(sm.z, w2.y, acc[m][1]);
                acc[m][2] = fmaf(sm.z, w2.z, acc[m][2]);
                acc[m][3] = fmaf(sm.z, w2.w, acc[m][3]);
                acc[m][0] = fmaf(sm.w, w3.x, acc[m][0]);
                acc[m][1] = fmaf(sm.w, w3.y, acc[m][1]);
                acc[m][2] = fmaf(sm.w, w3.z, acc[m][2]);
                acc[m][3] = fmaf(sm.w, w3.w, acc[m][3]);
            }
        }
    }
#pragma unroll
    for (int m = 0; m < RPM; m++) {
        size_t row = node0 + mg * RPM + m;
        float4 o = {acc[m][0], acc[m][1], acc[m][2], acc[m][3]};
        *(float4*)&OUT[row * F + cc] = o;
    }
}

// ---------------- combine: h = relu(bn(gather(y) + b + r)) ----------------
// thread owns 4 channels; edge loop 8-deep unrolled; fp chain bit-exact.
template <int F>
__global__ __launch_bounds__(256) void combine_kernel(const float* __restrict__ y,
        const float* __restrict__ r, const int* __restrict__ rowptr,
        const int* __restrict__ ssrc, const float* __restrict__ swt,
        const float* __restrict__ bias, const float* __restrict__ bg,
        const float* __restrict__ bb, const float* __restrict__ bm,
        const float* __restrict__ rs, float* __restrict__ h) {
    constexpr int TPN = F / 4;
    int tid = threadIdx.x;
    int node = blockIdx.x * (256 / TPN) + tid / TPN;
    int c = (tid % TPN) * 4;
    int e0 = rowptr[node], e1 = rowptr[node + 1];
    float4 acc = {0.f, 0.f, 0.f, 0.f};
    int e = e0;
    for (; e < e1 && (e & 3); ++e) {
        int s0 = ssrc[e]; float w0 = swt[e];
        float4 y0 = *(const float4*)&y[(size_t)s0 * F + c];
        acc.x = fmaf(w0, y0.x, acc.x); acc.y = fmaf(w0, y0.y, acc.y);
        acc.z = fmaf(w0, y0.z, acc.z); acc.w = fmaf(w0, y0.w, acc.w);
    }
    for (; e + 8 <= e1; e += 8) {
        int4   sa = *(const int4*)&ssrc[e];
        int4   sb = *(const int4*)&ssrc[e + 4];
        float4 wa = *(const float4*)&swt[e];
        float4 wb = *(const float4*)&swt[e + 4];
        float4 y0 = *(const float4*)&y[(size_t)sa.x * F + c];
        float4 y1 = *(const float4*)&y[(size_t)sa.y * F + c];
        float4 y2 = *(const float4*)&y[(size_t)sa.z * F + c];
        float4 y3 = *(const float4*)&y[(size_t)sa.w * F + c];
        float4 y4 = *(const float4*)&y[(size_t)sb.x * F + c];
        float4 y5 = *(const float4*)&y[(size_t)sb.y * F + c];
        float4 y6 = *(const float4*)&y[(size_t)sb.z * F + c];
        float4 y7 = *(const float4*)&y[(size_t)sb.w * F + c];
        acc.x = fmaf(wa.x, y0.x, acc.x); acc.y = fmaf(wa.x, y0.y, acc.y);
        acc.z = fmaf(wa.x, y0.z, acc.z); acc.w = fmaf(wa.x, y0.w, acc.w);
        acc.x = fmaf(wa.y, y1.x, acc.x); acc.y = fmaf(wa.y, y1.y, acc.y);
        acc.z = fmaf(wa.y, y1.z, acc.z); acc.w = fmaf(wa.y, y1.w, acc.w);
        acc.x = fmaf(wa.z, y2.x, acc.x); acc.y = fmaf(wa.z, y2.y, acc.y);
        acc.z = fmaf(wa.z, y2.z, acc.z); acc.w = fmaf(wa.z, y2.w, acc.w);
        acc.x = fmaf(wa.w, y3.x, acc.x); acc.y = fmaf(wa.w, y3.y, acc.y);
        acc.z = fmaf(wa.w, y3.z, acc.z); acc.w = fmaf(wa.w, y3.w, acc.w);
        acc.x = fmaf(wb.x, y4.x, acc.x); acc.y = fmaf(wb.x, y4.y, acc.y);
        acc.z = fmaf(wb.x, y4.z, acc.z); acc.w = fmaf(wb.x, y4.w, acc.w);
        acc.x = fmaf(wb.y, y5.x, acc.x); acc.y = fmaf(wb.y, y5.y, acc.y);
        acc.z = fmaf(wb.y, y5.z, acc.z); acc.w = fmaf(wb.y, y5.w, acc.w);
        acc.x = fmaf(wb.z, y6.x, acc.x); acc.y = fmaf(wb.z, y6.y, acc.y);
        acc.z = fmaf(wb.z, y6.z, acc.z); acc.w = fmaf(wb.z, y6.w, acc.w);
        acc.x = fmaf(wb.w, y7.x, acc.x); acc.y = fmaf(wb.w, y7.y, acc.y);
        acc.z = fmaf(wb.w, y7.z, acc.z); acc.w = fmaf(wb.w, y7.w, acc.w);
    }
    for (; e + 4 <= e1; e += 4) {
        int4   s4 = *(const int4*)&ssrc[e];
        float4 w4 = *(const float4*)&swt[e];
        float4 y0 = *(const float4*)&y[(size_t)s4.x * F + c];
        float4 y1 = *(const float4*)&y[(size_t)s4.y * F + c];
        float4 y2 = *(const float4*)&y[(size_t)s4.z * F + c];
        float4 y3 = *(const float4*)&y[(size_t)s4.w * F + c];
        acc.x = fmaf(w4.x, y0.x, acc.x); acc.y = fmaf(w4.x, y0.y, acc.y);
        acc.z = fmaf(w4.x, y0.z, acc.z); acc.w = fmaf(w4.x, y0.w, acc.w);
        acc.x = fmaf(w4.y, y1.x, acc.x); acc.y = fmaf(w4.y, y1.y, acc.y);
        acc.z = fmaf(w4.y, y1.z, acc.z); acc.w = fmaf(w4.y, y1.w, acc.w);
        acc.x = fmaf(w4.z, y2.x, acc.x); acc.y = fmaf(w4.z, y2.y, acc.y);
        acc.z = fmaf(w4.z, y2.z, acc.z); acc.w = fmaf(w4.z, y2.w, acc.w);
        acc.x = fmaf(w4.w, y3.x, acc.x); acc.y = fmaf(w4.w, y3.y, acc.y);
        acc.z = fmaf(w4.w, y3.z, acc.z); acc.w = fmaf(w4.w, y3.w, acc.w);
    }
    for (; e < e1; ++e) {
        int s0 = ssrc[e]; float w0 = swt[e];
        float4 y0 = *(const float4*)&y[(size_t)s0 * F + c];
        acc.x = fmaf(w0, y0.x, acc.x); acc.y = fmaf(w0, y0.y, acc.y);
        acc.z = fmaf(w0, y0.z, acc.z); acc.w = fmaf(w0, y0.w, acc.w);
    }
    float4 bi = *(const float4*)&bias[c];
    float4 rv = *(const float4*)&r[(size_t)node * F + c];
    float4 mu = *(const float4*)&bm[c];
    float4 rq = *(const float4*)&rs[c];
    float4 gm = *(const float4*)&bg[c];
    float4 bt = *(const float4*)&bb[c];
    float4 o;
    o.x = fmaxf((acc.x + bi.x + rv.x - mu.x) * rq.x * gm.x + bt.x, 0.f);
    o.y = fmaxf((acc.y + bi.y + rv.y - mu.y) * rq.y * gm.y + bt.y, 0.f);
    o.z = fmaxf((acc.z + bi.z + rv.z - mu.z) * rq.z * gm.z + bt.z, 0.f);
    o.w = fmaxf((acc.w + bi.w + rv.w - mu.w) * rq.w * gm.w + bt.w, 0.f);
    *(float4*)&h[(size_t)node * F + c] = o;
}

// ---------------- pool + fc + sigmoid ----------------
__global__ __launch_bounds__(256) void pool_fc_kernel(const float* __restrict__ h4,
        const int* __restrict__ starts, const float* __restrict__ fcw,
        const float* __restrict__ fcb, float* __restrict__ out) {
    int g = blockIdx.x;
    int tid = threadIdx.x;
    int i0 = starts[g], i1 = starts[g + 1];
    int ch = tid & 31, part = tid >> 5;
    float sum = 0.f;
    for (int i = i0 + part; i < i1; i += 8) sum += h4[(size_t)i * 32 + ch];
    __shared__ float sm[8][32];
    sm[part][ch] = sum;
    __syncthreads();
    if (tid < 32) {
        float tot = 0.f;
        for (int p = 0; p < 8; p++) tot += sm[p][tid];
        float cnt = (float)(i1 - i0);
        float mean = tot / fmaxf(cnt, 1.0f);
        sm[0][tid] = mean * fcw[tid];
    }
    __syncthreads();
    if (tid == 0) {
        float z = 0.f;
        for (int c = 0; c < 32; c++) z += sm[0][c];
        z += fcb[0];
        out[g] = 1.0f / (1.0f + expf(-z));
    }
}

extern "C" void kernel_launch(void* const* d_in, const int* in_sizes, int n_in,
                              void* d_out, int out_size, void* d_ws, size_t ws_size,
                              hipStream_t stream) {
    (void)in_sizes; (void)n_in; (void)out_size; (void)ws_size;
    const float* x       = (const float*)d_in[0];
    const int*   ei      = (const int*)d_in[1];
    const float* ew      = (const float*)d_in[2];
    const int*   batch   = (const int*)d_in[3];
    const float* w1_rel  = (const float*)d_in[4];
    const float* b1      = (const float*)d_in[5];
    const float* w1_root = (const float*)d_in[6];
    const float* w2_rel  = (const float*)d_in[7];
    const float* b2      = (const float*)d_in[8];
    const float* w2_root = (const float*)d_in[9];
    const float* w3_rel  = (const float*)d_in[10];
    const float* b3      = (const float*)d_in[11];
    const float* w3_root = (const float*)d_in[12];
    const float* w4_rel  = (const float*)d_in[13];
    const float* b4      = (const float*)d_in[14];
    const float* w4_root = (const float*)d_in[15];
    const float* bn1_g = (const float*)d_in[16];
    const float* bn1_b = (const float*)d_in[17];
    const float* bn1_m = (const float*)d_in[18];
    const float* bn2_g = (const float*)d_in[20];
    const float* bn2_b = (const float*)d_in[21];
    const float* bn2_m = (const float*)d_in[22];
    const float* bn3_g = (const float*)d_in[24];
    const float* bn3_b = (const float*)d_in[25];
    const float* bn3_m = (const float*)d_in[26];
    const float* fc_w = (const float*)d_in[28];
    const float* fc_b = (const float*)d_in[29];

    char* ws = (char*)d_ws;
    int*   rowptr = (int*)(ws + 0);                              // (N+1)*4
    int*   cnt    = (int*)(ws + (1ull << 20));                   // N*4 (hist/deg)
    int*   cnt2   = cnt + N_NODES;                               // N*4 (scatter pos)
    int*   bsum   = (int*)(ws + (2ull << 20));                   // 391*4
    float* rs     = (float*)(ws + (2ull << 20) + (64ull << 10)); // 224 floats
    int*   starts = (int*)(ws + (2ull << 20) + (128ull << 10));  // 257*4
    int*   ssrc   = (int*)(ws + (4ull << 20));                   // E*4 = 6.4MB
    float* swt    = (float*)(ws + (11ull << 20));                // E*4 = 6.4MB
    float* bufA   = (float*)(ws + (18ull << 20));                // 104MB: h1 / r3,h3
    float* bufB   = (float*)(ws + (122ull << 20));               // 52MB:  xp / y2 / y3 / y4
    float* bufC   = (float*)(ws + (174ull << 20));               // 52MB:  agg / r2,h2 / r4,h4
    float* xp   = bufB;   // [N,32] padded x; dead before gemm2 writes bufB
    float* agg1 = bufC;   // [N,32] padded agg; dead before gemm2 writes bufC

    // CSR build (reused by all 4 layers); one memset zeroes both counter arrays
    hipMemsetAsync(cnt, 0, 2 * N_NODES * 4, stream);
    hist_kernel<<<6250, 256, 0, stream>>>(ei, cnt);
    scan1_kernel<<<391, 256, 0, stream>>>(cnt, rowptr, bsum);
    scan2_kernel<<<1, 512, 0, stream>>>(bsum, 391);
    scan3_kernel<<<391, 256, 0, stream>>>(rowptr, bsum);
    scatter_kernel<<<6250, 256, 0, stream>>>(ei, ew, rowptr, cnt2, ssrc, swt);

    // fused prep: pad x + graph starts + bn rsqrt tables (one launch)
    prep_kernel<<<12500, 256, 0, stream>>>(x, xp, batch, starts,
                                           (const float*)d_in[19], (const float*)d_in[23],
                                           (const float*)d_in[27], rs);

    // layer 1 (29 -> 256), aggregate-first on padded x
    agg_x_kernel<<<3125, 256, 0, stream>>>(xp, rowptr, ssrc, swt, agg1);
    dense1_kernel<<<1563, 256, 0, stream>>>(agg1, xp, w1_rel, w1_root, b1, bufA);

    // layer 2 (256 -> 128): ROWS=64, KC=64 -> 16 KiB LDS
    gemm_dual_kernel<256, 128, 16, 64><<<1563, 256, 0, stream>>>(bufA, w2_rel, w2_root, bufB, bufC);
    combine_kernel<128><<<12500, 256, 0, stream>>>(bufB, bufC, rowptr, ssrc, swt,
                                                   b2, bn1_g, bn1_b, bn1_m, rs, bufC);

    // layer 3 (128 -> 64): ROWS=64, KC=64 -> 16 KiB LDS
    gemm_dual_kernel<128, 64, 8, 64><<<1563, 256, 0, stream>>>(bufC, w3_rel, w3_root, bufB, bufA);
    combine_kernel<64><<<6250, 256, 0, stream>>>(bufB, bufA, rowptr, ssrc, swt,
                                                 b3, bn2_g, bn2_b, bn2_m, rs + 128, bufA);

    // layer 4 (64 -> 32): ROWS=128, KC=32 -> 16 KiB LDS
    gemm_dual_kernel<64, 32, 8, 32><<<782, 256, 0, stream>>>(bufA, w4_rel, w4_root, bufB, bufC);
    combine_kernel<32><<<3125, 256, 0, stream>>>(bufB, bufC, rowptr, ssrc, swt,
                                                 b4, bn3_g, bn3_b, bn3_m, rs + 192, bufC);

    // pool + fc + sigmoid
    pool_fc_kernel<<<N_GRAPHS, 256, 0, stream>>>(bufC, starts, fc_w, fc_b, (float*)d_out);
}

// Round 14
// 766.122 us; speedup vs baseline: 1.9179x; 1.9179x over previous
//
#include <hip/hip_runtime.h>
#include <math.h>

#define N_NODES 100000
#define N_EDGES 1600000
#define N_GRAPHS 256
#define BN_EPS 1e-5f

// ---------------- CSR build ----------------
__global__ void hist_kernel(const int* __restrict__ ei, int* __restrict__ deg) {
    int e = blockIdx.x * blockDim.x + threadIdx.x;
    if (e < N_EDGES) atomicAdd(&deg[ei[N_EDGES + e]], 1);
}

__global__ void scan1_kernel(const int* __restrict__ deg, int* __restrict__ rowptr,
                             int* __restrict__ bsum) {
    __shared__ int s[256];
    int tid = threadIdx.x;
    int i = blockIdx.x * 256 + tid;
    int v = (i < N_NODES) ? deg[i] : 0;
    s[tid] = v; __syncthreads();
    for (int off = 1; off < 256; off <<= 1) {
        int t = (tid >= off) ? s[tid - off] : 0; __syncthreads();
        s[tid] += t; __syncthreads();
    }
    if (i < N_NODES) rowptr[i] = s[tid] - v;   // exclusive
    if (tid == 255) bsum[blockIdx.x] = s[255];
}

__global__ void scan2_kernel(int* bsum, int nb) {
    __shared__ int s[512];
    int tid = threadIdx.x;
    int v = (tid < nb) ? bsum[tid] : 0;
    s[tid] = v; __syncthreads();
    for (int off = 1; off < 512; off <<= 1) {
        int t = (tid >= off) ? s[tid - off] : 0; __syncthreads();
        s[tid] += t; __syncthreads();
    }
    if (tid < nb) bsum[tid] = s[tid] - v;      // exclusive
}

__global__ void scan3_kernel(int* __restrict__ rowptr, const int* __restrict__ bsum) {
    int i = blockIdx.x * 256 + threadIdx.x;
    if (i < N_NODES) rowptr[i] += bsum[blockIdx.x];
    if (i == 0) rowptr[N_NODES] = N_EDGES;
}

__global__ void scatter_kernel(const int* __restrict__ ei, const float* __restrict__ ew,
                               const int* __restrict__ rowptr, int* __restrict__ cnt,
                               int* __restrict__ ssrc, float* __restrict__ swt) {
    int e = blockIdx.x * blockDim.x + threadIdx.x;
    if (e >= N_EDGES) return;
    int dst = ei[N_EDGES + e];
    int pos = rowptr[dst] + atomicAdd(&cnt[dst], 1);
    ssrc[pos] = ei[e];
    swt[pos] = ew[e];
}

// ---------------- fused prep: pad_x + starts + bnprep (one launch) ----------------
__global__ __launch_bounds__(256) void prep_kernel(const float* __restrict__ x,
        float* __restrict__ xp, const int* __restrict__ batch,
        int* __restrict__ starts, const float* __restrict__ v1,
        const float* __restrict__ v2, const float* __restrict__ v3,
        float* __restrict__ rs) {
    int i = blockIdx.x * 256 + threadIdx.x;
    if (i < N_NODES * 32) {
        int n = i >> 5, c = i & 31;
        xp[i] = (c < 29) ? x[n * 29 + c] : 0.f;
    }
    if (i < N_NODES) {
        int b = batch[i];
        int bp = (i == 0) ? -1 : batch[i - 1];
        for (int g = bp + 1; g <= b; ++g) starts[g] = i;
        if (i == N_NODES - 1)
            for (int g = b + 1; g <= N_GRAPHS; ++g) starts[g] = N_NODES;
    }
    if (blockIdx.x == 12499) {
        int t = threadIdx.x;
        if (t < 128) rs[t] = 1.0f / sqrtf(v1[t] + BN_EPS);
        if (t < 64)  rs[128 + t] = 1.0f / sqrtf(v2[t] + BN_EPS);
        if (t < 32)  rs[192 + t] = 1.0f / sqrtf(v3[t] + BN_EPS);
    }
}

// ---------------- layer-1 gather on padded x: agg[N,32] ----------------
__global__ __launch_bounds__(256) void agg_x_kernel(const float* __restrict__ xp,
        const int* __restrict__ rowptr, const int* __restrict__ ssrc,
        const float* __restrict__ swt, float* __restrict__ agg) {
    int tid = threadIdx.x;
    int node = blockIdx.x * 32 + (tid >> 3);
    int c = (tid & 7) * 4;
    int e0 = rowptr[node], e1 = rowptr[node + 1];
    float4 acc = {0.f, 0.f, 0.f, 0.f};
    int e = e0;
    // align e to 4 (order-preserving)
    for (; e < e1 && (e & 3); ++e) {
        int s0 = ssrc[e]; float w0 = swt[e];
        float4 y0 = *(const float4*)&xp[(size_t)s0 * 32 + c];
        acc.x = fmaf(w0, y0.x, acc.x); acc.y = fmaf(w0, y0.y, acc.y);
        acc.z = fmaf(w0, y0.z, acc.z); acc.w = fmaf(w0, y0.w, acc.w);
    }
    for (; e + 8 <= e1; e += 8) {
        int4   sa = *(const int4*)&ssrc[e];
        int4   sb = *(const int4*)&ssrc[e + 4];
        float4 wa = *(const float4*)&swt[e];
        float4 wb = *(const float4*)&swt[e + 4];
        float4 y0 = *(const float4*)&xp[(size_t)sa.x * 32 + c];
        float4 y1 = *(const float4*)&xp[(size_t)sa.y * 32 + c];
        float4 y2 = *(const float4*)&xp[(size_t)sa.z * 32 + c];
        float4 y3 = *(const float4*)&xp[(size_t)sa.w * 32 + c];
        float4 y4 = *(const float4*)&xp[(size_t)sb.x * 32 + c];
        float4 y5 = *(const float4*)&xp[(size_t)sb.y * 32 + c];
        float4 y6 = *(const float4*)&xp[(size_t)sb.z * 32 + c];
        float4 y7 = *(const float4*)&xp[(size_t)sb.w * 32 + c];
        acc.x = fmaf(wa.x, y0.x, acc.x); acc.y = fmaf(wa.x, y0.y, acc.y);
        acc.z = fmaf(wa.x, y0.z, acc.z); acc.w = fmaf(wa.x, y0.w, acc.w);
        acc.x = fmaf(wa.y, y1.x, acc.x); acc.y = fmaf(wa.y, y1.y, acc.y);
        acc.z = fmaf(wa.y, y1.z, acc.z); acc.w = fmaf(wa.y, y1.w, acc.w);
        acc.x = fmaf(wa.z, y2.x, acc.x); acc.y = fmaf(wa.z, y2.y, acc.y);
        acc.z = fmaf(wa.z, y2.z, acc.z); acc.w = fmaf(wa.z, y2.w, acc.w);
        acc.x = fmaf(wa.w, y3.x, acc.x); acc.y = fmaf(wa.w, y3.y, acc.y);
        acc.z = fmaf(wa.w, y3.z, acc.z); acc.w = fmaf(wa.w, y3.w, acc.w);
        acc.x = fmaf(wb.x, y4.x, acc.x); acc.y = fmaf(wb.x, y4.y, acc.y);
        acc.z = fmaf(wb.x, y4.z, acc.z); acc.w = fmaf(wb.x, y4.w, acc.w);
        acc.x = fmaf(wb.y, y5.x, acc.x); acc.y = fmaf(wb.y, y5.y, acc.y);
        acc.z = fmaf(wb.y, y5.z, acc.z); acc.w = fmaf(wb.y, y5.w, acc.w);
        acc.x = fmaf(wb.z, y6.x, acc.x); acc.y = fmaf(wb.z, y6.y, acc.y);
        acc.z = fmaf(wb.z, y6.z, acc.z); acc.w = fmaf(wb.z, y6.w, acc.w);
        acc.x = fmaf(wb.w, y7.x, acc.x); acc.y = fmaf(wb.w, y7.y, acc.y);
        acc.z = fmaf(wb.w, y7.z, acc.z); acc.w = fmaf(wb.w, y7.w, acc.w);
    }
    for (; e + 4 <= e1; e += 4) {
        int4   s4 = *(const int4*)&ssrc[e];
        float4 w4 = *(const float4*)&swt[e];
        float4 y0 = *(const float4*)&xp[(size_t)s4.x * 32 + c];
        float4 y1 = *(const float4*)&xp[(size_t)s4.y * 32 + c];
        float4 y2 = *(const float4*)&xp[(size_t)s4.z * 32 + c];
        float4 y3 = *(const float4*)&xp[(size_t)s4.w * 32 + c];
        acc.x = fmaf(w4.x, y0.x, acc.x); acc.y = fmaf(w4.x, y0.y, acc.y);
        acc.z = fmaf(w4.x, y0.z, acc.z); acc.w = fmaf(w4.x, y0.w, acc.w);
        acc.x = fmaf(w4.y, y1.x, acc.x); acc.y = fmaf(w4.y, y1.y, acc.y);
        acc.z = fmaf(w4.y, y1.z, acc.z); acc.w = fmaf(w4.y, y1.w, acc.w);
        acc.x = fmaf(w4.z, y2.x, acc.x); acc.y = fmaf(w4.z, y2.y, acc.y);
        acc.z = fmaf(w4.z, y2.z, acc.z); acc.w = fmaf(w4.z, y2.w, acc.w);
        acc.x = fmaf(w4.w, y3.x, acc.x); acc.y = fmaf(w4.w, y3.y, acc.y);
        acc.z = fmaf(w4.w, y3.z, acc.z); acc.w = fmaf(w4.w, y3.w, acc.w);
    }
    for (; e < e1; ++e) {
        int s0 = ssrc[e]; float w0 = swt[e];
        float4 y0 = *(const float4*)&xp[(size_t)s0 * 32 + c];
        acc.x = fmaf(w0, y0.x, acc.x); acc.y = fmaf(w0, y0.y, acc.y);
        acc.z = fmaf(w0, y0.z, acc.z); acc.w = fmaf(w0, y0.w, acc.w);
    }
    *(float4*)&agg[(size_t)node * 32 + c] = acc;
}

// h1 = relu(agg @ w1_rel + b1 + x @ w1_root), [N,256]; agg/xp padded stride 32.
// 64 rows/block; LDS reads wave-uniform broadcasts; fmaf chain bit-exact.
__global__ __launch_bounds__(256) void dense1_kernel(const float* __restrict__ agg,
        const float* __restrict__ xp, const float* __restrict__ wrel,
        const float* __restrict__ wroot, const float* __restrict__ bias,
        float* __restrict__ out) {
    __shared__ float sA[64 * 32];
    __shared__ float sX[64 * 32];
    int tid = threadIdx.x;
    size_t node0 = (size_t)blockIdx.x * 64;
    for (int idx = tid; idx < 512; idx += 256) {
        ((float4*)sA)[idx] = ((const float4*)(agg + node0 * 32))[idx];
        ((float4*)sX)[idx] = ((const float4*)(xp + node0 * 32))[idx];
    }
    __syncthreads();
    int ct = tid & 63;      // 64 col-tiles of 4
    int mg = tid >> 6;      // 4 m-groups of 16 rows
    int c0 = ct * 4;
    float acc[16][4];
#pragma unroll
    for (int m = 0; m < 16; m++)
#pragma unroll
        for (int j = 0; j < 4; j++) acc[m][j] = 0.f;
    for (int k0 = 0; k0 < 28; k0 += 4) {
        float4 wr[4], wo[4];
#pragma unroll
        for (int j = 0; j < 4; j++) {
            wr[j] = *(const float4*)&wrel[(k0 + j) * 256 + c0];
            wo[j] = *(const float4*)&wroot[(k0 + j) * 256 + c0];
        }
#pragma unroll
        for (int m = 0; m < 16; m++) {
            float4 av = *(const float4*)&sA[(mg * 16 + m) * 32 + k0];
            float4 xv = *(const float4*)&sX[(mg * 16 + m) * 32 + k0];
            float as[4] = {av.x, av.y, av.z, av.w};
            float xs[4] = {xv.x, xv.y, xv.z, xv.w};
#pragma unroll
            for (int j = 0; j < 4; j++) {
                acc[m][0] = fmaf(as[j], wr[j].x, fmaf(xs[j], wo[j].x, acc[m][0]));
                acc[m][1] = fmaf(as[j], wr[j].y, fmaf(xs[j], wo[j].y, acc[m][1]));
                acc[m][2] = fmaf(as[j], wr[j].z, fmaf(xs[j], wo[j].z, acc[m][2]));
                acc[m][3] = fmaf(as[j], wr[j].w, fmaf(xs[j], wo[j].w, acc[m][3]));
            }
        }
    }
    {   // tail k = 28
        float4 wr = *(const float4*)&wrel[28 * 256 + c0];
        float4 wo = *(const float4*)&wroot[28 * 256 + c0];
#pragma unroll
        for (int m = 0; m < 16; m++) {
            float sa = sA[(mg * 16 + m) * 32 + 28];
            float sx = sX[(mg * 16 + m) * 32 + 28];
            acc[m][0] = fmaf(sa, wr.x, fmaf(sx, wo.x, acc[m][0]));
            acc[m][1] = fmaf(sa, wr.y, fmaf(sx, wo.y, acc[m][1]));
            acc[m][2] = fmaf(sa, wr.z, fmaf(sx, wo.z, acc[m][2]));
            acc[m][3] = fmaf(sa, wr.w, fmaf(sx, wo.w, acc[m][3]));
        }
    }
    float4 b4 = *(const float4*)&bias[c0];
#pragma unroll
    for (int m = 0; m < 16; m++) {
        size_t row = node0 + mg * 16 + m;
        float4 o;
        o.x = fmaxf(acc[m][0] + b4.x, 0.f);
        o.y = fmaxf(acc[m][1] + b4.y, 0.f);
        o.z = fmaxf(acc[m][2] + b4.z, 0.f);
        o.w = fmaxf(acc[m][3] + b4.w, 0.f);
        *(float4*)&out[row * 256 + c0] = o;
    }
}

// ---------------- dual GEMM: y = in@wA, r = in@wB  ([N,K] @ [K,F]) ----------------
// R4 structure, converged at 197 us (9 schedule variants null/worse; the R13
// __launch_bounds__(256,8) hint forced VGPR 52->32 and spilled acc to scratch:
// WRITE 100MB->2.6GB, 934 us — plain (256) is correct). 52 VGPR, 16 KiB LDS.
template <int K, int F, int RPM, int KC>
__global__ __launch_bounds__(256) void gemm_dual_kernel(const float* __restrict__ in,
        const float* __restrict__ wA, const float* __restrict__ wB,
        float* __restrict__ outA, float* __restrict__ outB) {
    constexpr int NT = 256;
    constexpr int NCT = F / 2;        // col-groups of 4 over 2F output cols
    constexpr int MG = NT / NCT;
    constexpr int ROWS = MG * RPM;
    constexpr int KC4 = KC / 4;
    __shared__ float s[ROWS * KC];
    int tid = threadIdx.x;
    size_t node0 = (size_t)blockIdx.x * ROWS;
    int ct = tid % NCT;
    int mg = tid / NCT;
    int c0 = ct * 4;
    const float* W;
    float* OUT;
    int cc;
    if (c0 < F) { W = wA; OUT = outA; cc = c0; }
    else        { W = wB; OUT = outB; cc = c0 - F; }
    float acc[RPM][4];
#pragma unroll
    for (int m = 0; m < RPM; m++)
#pragma unroll
        for (int j = 0; j < 4; j++) acc[m][j] = 0.f;
    const float* srow = s + (size_t)(mg * RPM) * KC;
    for (int kb = 0; kb < K; kb += KC) {
        __syncthreads();
        for (int idx = tid; idx < ROWS * KC4; idx += NT) {
            int rr = idx / KC4;
            int c4 = idx % KC4;
            *(float4*)&s[rr * KC + c4 * 4] =
                *(const float4*)&in[(node0 + rr) * K + kb + c4 * 4];
        }
        __syncthreads();
        for (int k0 = 0; k0 < KC; k0 += 4) {
            float4 w0 = *(const float4*)&W[(kb + k0 + 0) * F + cc];
            float4 w1 = *(const float4*)&W[(kb + k0 + 1) * F + cc];
            float4 w2 = *(const float4*)&W[(kb + k0 + 2) * F + cc];
            float4 w3 = *(const float4*)&W[(kb + k0 + 3) * F + cc];
#pragma unroll
            for (int m = 0; m < RPM; m++) {
                float4 sm = *(const float4*)&srow[m * KC + k0];
                acc[m][0] = fmaf(sm.x, w0.x, acc[m][0]);
                acc[m][1] = fmaf(sm.x, w0.y, acc[m][1]);
                acc[m][2] = fmaf(sm.x, w0.z, acc[m][2]);
                acc[m][3] = fmaf(sm.x, w0.w, acc[m][3]);
                acc[m][0] = fmaf(sm.y, w1.x, acc[m][0]);
                acc[m][1] = fmaf(sm.y, w1.y, acc[m][1]);
                acc[m][2] = fmaf(sm.y, w1.z, acc[m][2]);
                acc[m][3] = fmaf(sm.y, w1.w, acc[m][3]);
                acc[m][0] = fmaf(sm.z, w2.x, acc[m][0]);
                acc[m][1] = fmaf(sm.z, w2.y, acc[m][1]);
                acc[m][2] = fmaf(sm.z, w2.z, acc[m][2]);
                acc[m][3] = fmaf(sm.z, w2.w, acc[m][3]);
                acc[m][0] = fmaf(sm.w, w3.x, acc[m][0]);
                acc[m][1] = fmaf(sm.w, w3.y, acc[m][1]);
                acc[m][2] = fmaf(sm.w, w3.z, acc[m][2]);
                acc[m][3] = fmaf(sm.w, w3.w, acc[m][3]);
            }
        }
    }
#pragma unroll
    for (int m = 0; m < RPM; m++) {
        size_t row = node0 + mg * RPM + m;
        float4 o = {acc[m][0], acc[m][1], acc[m][2], acc[m][3]};
        *(float4*)&OUT[row * F + cc] = o;
    }
}

// ---------------- combine: h = relu(bn(gather(y) + b + r)) ----------------
// thread owns 4 channels; edge loop 8-deep unrolled; fp chain bit-exact.
template <int F>
__global__ __launch_bounds__(256) void combine_kernel(const float* __restrict__ y,
        const float* __restrict__ r, const int* __restrict__ rowptr,
        const int* __restrict__ ssrc, const float* __restrict__ swt,
        const float* __restrict__ bias, const float* __restrict__ bg,
        const float* __restrict__ bb, const float* __restrict__ bm,
        const float* __restrict__ rs, float* __restrict__ h) {
    constexpr int TPN = F / 4;
    int tid = threadIdx.x;
    int node = blockIdx.x * (256 / TPN) + tid / TPN;
    int c = (tid % TPN) * 4;
    int e0 = rowptr[node], e1 = rowptr[node + 1];
    float4 acc = {0.f, 0.f, 0.f, 0.f};
    int e = e0;
    for (; e < e1 && (e & 3); ++e) {
        int s0 = ssrc[e]; float w0 = swt[e];
        float4 y0 = *(const float4*)&y[(size_t)s0 * F + c];
        acc.x = fmaf(w0, y0.x, acc.x); acc.y = fmaf(w0, y0.y, acc.y);
        acc.z = fmaf(w0, y0.z, acc.z); acc.w = fmaf(w0, y0.w, acc.w);
    }
    for (; e + 8 <= e1; e += 8) {
        int4   sa = *(const int4*)&ssrc[e];
        int4   sb = *(const int4*)&ssrc[e + 4];
        float4 wa = *(const float4*)&swt[e];
        float4 wb = *(const float4*)&swt[e + 4];
        float4 y0 = *(const float4*)&y[(size_t)sa.x * F + c];
        float4 y1 = *(const float4*)&y[(size_t)sa.y * F + c];
        float4 y2 = *(const float4*)&y[(size_t)sa.z * F + c];
        float4 y3 = *(const float4*)&y[(size_t)sa.w * F + c];
        float4 y4 = *(const float4*)&y[(size_t)sb.x * F + c];
        float4 y5 = *(const float4*)&y[(size_t)sb.y * F + c];
        float4 y6 = *(const float4*)&y[(size_t)sb.z * F + c];
        float4 y7 = *(const float4*)&y[(size_t)sb.w * F + c];
        acc.x = fmaf(wa.x, y0.x, acc.x); acc.y = fmaf(wa.x, y0.y, acc.y);
        acc.z = fmaf(wa.x, y0.z, acc.z); acc.w = fmaf(wa.x, y0.w, acc.w);
        acc.x = fmaf(wa.y, y1.x, acc.x); acc.y = fmaf(wa.y, y1.y, acc.y);
        acc.z = fmaf(wa.y, y1.z, acc.z); acc.w = fmaf(wa.y, y1.w, acc.w);
        acc.x = fmaf(wa.z, y2.x, acc.x); acc.y = fmaf(wa.z, y2.y, acc.y);
        acc.z = fmaf(wa.z, y2.z, acc.z); acc.w = fmaf(wa.z, y2.w, acc.w);
        acc.x = fmaf(wa.w, y3.x, acc.x); acc.y = fmaf(wa.w, y3.y, acc.y);
        acc.z = fmaf(wa.w, y3.z, acc.z); acc.w = fmaf(wa.w, y3.w, acc.w);
        acc.x = fmaf(wb.x, y4.x, acc.x); acc.y = fmaf(wb.x, y4.y, acc.y);
        acc.z = fmaf(wb.x, y4.z, acc.z); acc.w = fmaf(wb.x, y4.w, acc.w);
        acc.x = fmaf(wb.y, y5.x, acc.x); acc.y = fmaf(wb.y, y5.y, acc.y);
        acc.z = fmaf(wb.y, y5.z, acc.z); acc.w = fmaf(wb.y, y5.w, acc.w);
        acc.x = fmaf(wb.z, y6.x, acc.x); acc.y = fmaf(wb.z, y6.y, acc.y);
        acc.z = fmaf(wb.z, y6.z, acc.z); acc.w = fmaf(wb.z, y6.w, acc.w);
        acc.x = fmaf(wb.w, y7.x, acc.x); acc.y = fmaf(wb.w, y7.y, acc.y);
        acc.z = fmaf(wb.w, y7.z, acc.z); acc.w = fmaf(wb.w, y7.w, acc.w);
    }
    for (; e + 4 <= e1; e += 4) {
        int4   s4 = *(const int4*)&ssrc[e];
        float4 w4 = *(const float4*)&swt[e];
        float4 y0 = *(const float4*)&y[(size_t)s4.x * F + c];
        float4 y1 = *(const float4*)&y[(size_t)s4.y * F + c];
        float4 y2 = *(const float4*)&y[(size_t)s4.z * F + c];
        float4 y3 = *(const float4*)&y[(size_t)s4.w * F + c];
        acc.x = fmaf(w4.x, y0.x, acc.x); acc.y = fmaf(w4.x, y0.y, acc.y);
        acc.z = fmaf(w4.x, y0.z, acc.z); acc.w = fmaf(w4.x, y0.w, acc.w);
        acc.x = fmaf(w4.y, y1.x, acc.x); acc.y = fmaf(w4.y, y1.y, acc.y);
        acc.z = fmaf(w4.y, y1.z, acc.z); acc.w = fmaf(w4.y, y1.w, acc.w);
        acc.x = fmaf(w4.z, y2.x, acc.x); acc.y = fmaf(w4.z, y2.y, acc.y);
        acc.z = fmaf(w4.z, y2.z, acc.z); acc.w = fmaf(w4.z, y2.w, acc.w);
        acc.x = fmaf(w4.w, y3.x, acc.x); acc.y = fmaf(w4.w, y3.y, acc.y);
        acc.z = fmaf(w4.w, y3.z, acc.z); acc.w = fmaf(w4.w, y3.w, acc.w);
    }
    for (; e < e1; ++e) {
        int s0 = ssrc[e]; float w0 = swt[e];
        float4 y0 = *(const float4*)&y[(size_t)s0 * F + c];
        acc.x = fmaf(w0, y0.x, acc.x); acc.y = fmaf(w0, y0.y, acc.y);
        acc.z = fmaf(w0, y0.z, acc.z); acc.w = fmaf(w0, y0.w, acc.w);
    }
    float4 bi = *(const float4*)&bias[c];
    float4 rv = *(const float4*)&r[(size_t)node * F + c];
    float4 mu = *(const float4*)&bm[c];
    float4 rq = *(const float4*)&rs[c];
    float4 gm = *(const float4*)&bg[c];
    float4 bt = *(const float4*)&bb[c];
    float4 o;
    o.x = fmaxf((acc.x + bi.x + rv.x - mu.x) * rq.x * gm.x + bt.x, 0.f);
    o.y = fmaxf((acc.y + bi.y + rv.y - mu.y) * rq.y * gm.y + bt.y, 0.f);
    o.z = fmaxf((acc.z + bi.z + rv.z - mu.z) * rq.z * gm.z + bt.z, 0.f);
    o.w = fmaxf((acc.w + bi.w + rv.w - mu.w) * rq.w * gm.w + bt.w, 0.f);
    *(float4*)&h[(size_t)node * F + c] = o;
}

// ---------------- pool + fc + sigmoid ----------------
__global__ __launch_bounds__(256) void pool_fc_kernel(const float* __restrict__ h4,
        const int* __restrict__ starts, const float* __restrict__ fcw,
        const float* __restrict__ fcb, float* __restrict__ out) {
    int g = blockIdx.x;
    int tid = threadIdx.x;
    int i0 = starts[g], i1 = starts[g + 1];
    int ch = tid & 31, part = tid >> 5;
    float sum = 0.f;
    for (int i = i0 + part; i < i1; i += 8) sum += h4[(size_t)i * 32 + ch];
    __shared__ float sm[8][32];
    sm[part][ch] = sum;
    __syncthreads();
    if (tid < 32) {
        float tot = 0.f;
        for (int p = 0; p < 8; p++) tot += sm[p][tid];
        float cnt = (float)(i1 - i0);
        float mean = tot / fmaxf(cnt, 1.0f);
        sm[0][tid] = mean * fcw[tid];
    }
    __syncthreads();
    if (tid == 0) {
        float z = 0.f;
        for (int c = 0; c < 32; c++) z += sm[0][c];
        z += fcb[0];
        out[g] = 1.0f / (1.0f + expf(-z));
    }
}

extern "C" void kernel_launch(void* const* d_in, const int* in_sizes, int n_in,
                              void* d_out, int out_size, void* d_ws, size_t ws_size,
                              hipStream_t stream) {
    (void)in_sizes; (void)n_in; (void)out_size; (void)ws_size;
    const float* x       = (const float*)d_in[0];
    const int*   ei      = (const int*)d_in[1];
    const float* ew      = (const float*)d_in[2];
    const int*   batch   = (const int*)d_in[3];
    const float* w1_rel  = (const float*)d_in[4];
    const float* b1      = (const float*)d_in[5];
    const float* w1_root = (const float*)d_in[6];
    const float* w2_rel  = (const float*)d_in[7];
    const float* b2      = (const float*)d_in[8];
    const float* w2_root = (const float*)d_in[9];
    const float* w3_rel  = (const float*)d_in[10];
    const float* b3      = (const float*)d_in[11];
    const float* w3_root = (const float*)d_in[12];
    const float* w4_rel  = (const float*)d_in[13];
    const float* b4      = (const float*)d_in[14];
    const float* w4_root = (const float*)d_in[15];
    const float* bn1_g = (const float*)d_in[16];
    const float* bn1_b = (const float*)d_in[17];
    const float* bn1_m = (const float*)d_in[18];
    const float* bn2_g = (const float*)d_in[20];
    const float* bn2_b = (const float*)d_in[21];
    const float* bn2_m = (const float*)d_in[22];
    const float* bn3_g = (const float*)d_in[24];
    const float* bn3_b = (const float*)d_in[25];
    const float* bn3_m = (const float*)d_in[26];
    const float* fc_w = (const float*)d_in[28];
    const float* fc_b = (const float*)d_in[29];

    char* ws = (char*)d_ws;
    int*   rowptr = (int*)(ws + 0);                              // (N+1)*4
    int*   cnt    = (int*)(ws + (1ull << 20));                   // N*4 (hist/deg)
    int*   cnt2   = cnt + N_NODES;                               // N*4 (scatter pos)
    int*   bsum   = (int*)(ws + (2ull << 20));                   // 391*4
    float* rs     = (float*)(ws + (2ull << 20) + (64ull << 10)); // 224 floats
    int*   starts = (int*)(ws + (2ull << 20) + (128ull << 10));  // 257*4
    int*   ssrc   = (int*)(ws + (4ull << 20));                   // E*4 = 6.4MB
    float* swt    = (float*)(ws + (11ull << 20));                // E*4 = 6.4MB
    float* bufA   = (float*)(ws + (18ull << 20));                // 104MB: h1 / r3,h3
    float* bufB   = (float*)(ws + (122ull << 20));               // 52MB:  xp / y2 / y3 / y4
    float* bufC   = (float*)(ws + (174ull << 20));               // 52MB:  agg / r2,h2 / r4,h4
    float* xp   = bufB;   // [N,32] padded x; dead before gemm2 writes bufB
    float* agg1 = bufC;   // [N,32] padded agg; dead before gemm2 writes bufC

    // CSR build (reused by all 4 layers); one memset zeroes both counter arrays
    hipMemsetAsync(cnt, 0, 2 * N_NODES * 4, stream);
    hist_kernel<<<6250, 256, 0, stream>>>(ei, cnt);
    scan1_kernel<<<391, 256, 0, stream>>>(cnt, rowptr, bsum);
    scan2_kernel<<<1, 512, 0, stream>>>(bsum, 391);
    scan3_kernel<<<391, 256, 0, stream>>>(rowptr, bsum);
    scatter_kernel<<<6250, 256, 0, stream>>>(ei, ew, rowptr, cnt2, ssrc, swt);

    // fused prep: pad x + graph starts + bn rsqrt tables (one launch)
    prep_kernel<<<12500, 256, 0, stream>>>(x, xp, batch, starts,
                                           (const float*)d_in[19], (const float*)d_in[23],
                                           (const float*)d_in[27], rs);

    // layer 1 (29 -> 256), aggregate-first on padded x
    agg_x_kernel<<<3125, 256, 0, stream>>>(xp, rowptr, ssrc, swt, agg1);
    dense1_kernel<<<1563, 256, 0, stream>>>(agg1, xp, w1_rel, w1_root, b1, bufA);

    // layer 2 (256 -> 128): ROWS=64, KC=64 -> 16 KiB LDS
    gemm_dual_kernel<256, 128, 16, 64><<<1563, 256, 0, stream>>>(bufA, w2_rel, w2_root, bufB, bufC);
    combine_kernel<128><<<12500, 256, 0, stream>>>(bufB, bufC, rowptr, ssrc, swt,
                                                   b2, bn1_g, bn1_b, bn1_m, rs, bufC);

    // layer 3 (128 -> 64): ROWS=64, KC=64 -> 16 KiB LDS
    gemm_dual_kernel<128, 64, 8, 64><<<1563, 256, 0, stream>>>(bufC, w3_rel, w3_root, bufB, bufA);
    combine_kernel<64><<<6250, 256, 0, stream>>>(bufB, bufA, rowptr, ssrc, swt,
                                                 b3, bn2_g, bn2_b, bn2_m, rs + 128, bufA);

    // layer 4 (64 -> 32): ROWS=128, KC=32 -> 16 KiB LDS
    gemm_dual_kernel<64, 32, 8, 32><<<782, 256, 0, stream>>>(bufA, w4_rel, w4_root, bufB, bufC);
    combine_kernel<32><<<3125, 256, 0, stream>>>(bufB, bufC, rowptr, ssrc, swt,
                                                 b4, bn3_g, bn3_b, bn3_m, rs + 192, bufC);

    // pool + fc + sigmoid
    pool_fc_kernel<<<N_GRAPHS, 256, 0, stream>>>(bufC, starts, fc_w, fc_b, (float*)d_out);
}